// Round 6
// baseline (495.146 us; speedup 1.0000x reference)
//
#include <hip/hip_runtime.h>
#include <math.h>

#define BB 8
#define MM 2048
#define NNP 2048
#define THR2 0.25f
#define NITER 10
#define SLOTS (NITER + 1)
#define NPART 17
#define TPB 1024
#define WPB 16                  // waves per block (8 pairs)
#define GRIDB 256               // one block per CU
#define BPB (GRIDB / BB)        // 32 blocks per batch
#define TM 8                    // source points per wave-pair
#define HALF (NNP / 2)          // dest points per wave of a pair
#define STEPS (HALF / 64)       // 16 ds_read_b128 per wave per iteration

// ---- ws layout (element counts) ----
#define ACC_N (SLOTS * BB * 32)     // float accum[SLOTS][BB][32] (17 used)
#define CN_N  (SLOTS * BB)          // uint arrive

__device__ inline float ld_acq_f(const float* p) {
    return __hip_atomic_load(p, __ATOMIC_ACQUIRE, __HIP_MEMORY_SCOPE_AGENT);
}
__device__ inline unsigned ld_acq_u(const unsigned* p) {
    return __hip_atomic_load(p, __ATOMIC_ACQUIRE, __HIP_MEMORY_SCOPE_AGENT);
}

// ---------------- zero the sync/accumulator region (every call: replay-safe) ----------------
__global__ void zero_kernel(float* __restrict__ accum, unsigned* __restrict__ arrive)
{
    const int tid = blockIdx.x * blockDim.x + threadIdx.x;
    if (tid < ACC_N) __hip_atomic_store(&accum[tid], 0.0f, __ATOMIC_RELAXED, __HIP_MEMORY_SCOPE_AGENT);
    if (tid < CN_N)  __hip_atomic_store(&arrive[tid], 0u, __ATOMIC_RELAXED, __HIP_MEMORY_SCOPE_AGENT);
}

// ---------------- Kabsch via Jacobi eigen of H^T H (float, H normalized ~O(1)) ----------------
__device__ void kabsch3f(const float H[3][3], float R[3][3])
{
    float A[3][3];
    for (int i = 0; i < 3; ++i)
        for (int j = 0; j < 3; ++j) {
            float s = 0.0f;
            for (int k = 0; k < 3; ++k) s += H[k][i] * H[k][j];
            A[i][j] = s;
        }
    float V[3][3] = {{1,0,0},{0,1,0},{0,0,1}};
    const float nrm = A[0][0]*A[0][0] + A[1][1]*A[1][1] + A[2][2]*A[2][2] + 1e-30f;
    for (int sweep = 0; sweep < 8; ++sweep) {
        const float off = A[0][1]*A[0][1] + A[0][2]*A[0][2] + A[1][2]*A[1][2];
        if (off < 1e-14f * nrm) break;
        for (int pi = 0; pi < 3; ++pi) {
            const int p = (pi == 2) ? 1 : 0;
            const int q = (pi == 0) ? 1 : 2;
            const float apq = A[p][q];
            if (apq == 0.0f) continue;
            const float theta = (A[q][q] - A[p][p]) / (2.0f * apq);
            const float t = ((theta >= 0.0f) ? 1.0f : -1.0f) / (fabsf(theta) + sqrtf(theta * theta + 1.0f));
            const float c = 1.0f / sqrtf(t * t + 1.0f);
            const float s = t * c;
            const float app = A[p][p], aqq = A[q][q];
            A[p][p] = app - t * apq;
            A[q][q] = aqq + t * apq;
            A[p][q] = 0.0f; A[q][p] = 0.0f;
            const int r = 3 - p - q;
            const float arp = A[r][p], arq = A[r][q];
            A[r][p] = c * arp - s * arq; A[p][r] = A[r][p];
            A[r][q] = s * arp + c * arq; A[q][r] = A[r][q];
            for (int rr = 0; rr < 3; ++rr) {
                const float vrp = V[rr][p], vrq = V[rr][q];
                V[rr][p] = c * vrp - s * vrq;
                V[rr][q] = s * vrp + c * vrq;
            }
        }
    }
    float lam[3] = {A[0][0], A[1][1], A[2][2]};
    int ord[3] = {0, 1, 2};
    for (int i = 0; i < 2; ++i)
        for (int j = i + 1; j < 3; ++j)
            if (lam[ord[j]] > lam[ord[i]]) { const int tmp = ord[i]; ord[i] = ord[j]; ord[j] = tmp; }
    float Vs[3][3], U[3][3];
    for (int k = 0; k < 3; ++k) {
        const int c0 = ord[k];
        const float sk = sqrtf(fmaxf(lam[c0], 0.0f));
        const float inv = (sk > 1e-12f) ? 1.0f / sk : 0.0f;
        for (int i = 0; i < 3; ++i) {
            Vs[i][k] = V[i][c0];
            U[i][k] = (H[i][0] * V[0][c0] + H[i][1] * V[1][c0] + H[i][2] * V[2][c0]) * inv;
        }
    }
    const float detH = H[0][0] * (H[1][1] * H[2][2] - H[1][2] * H[2][1])
                     - H[0][1] * (H[1][0] * H[2][2] - H[1][2] * H[2][0])
                     + H[0][2] * (H[1][0] * H[2][1] - H[1][1] * H[2][0]);
    const float d = (detH < 0.0f) ? -1.0f : 1.0f;
    for (int i = 0; i < 3; ++i)
        for (int j = 0; j < 3; ++j)
            R[i][j] = Vs[i][0] * U[j][0] + Vs[i][1] * U[j][1] + d * Vs[i][2] * U[j][2];
}

// ---------------- fused ICP: wave-pairs split dest, all-poll sync, XCD-local batches ----------------
__global__ __launch_bounds__(TPB, 4) void icp_fused(
    const float* __restrict__ pc_src,
    const float* __restrict__ pc_dest,
    const float* __restrict__ init_R,
    const float* __restrict__ init_t,
    float* __restrict__ accum,          // [SLOTS][BB][32]
    unsigned* __restrict__ arrive,      // [SLOTS][BB]
    float* __restrict__ out)
{
    const int blk = blockIdx.x;
    const int b = blk & 7;              // batch -> XCD (round-robin dispatch heuristic)
    const int cblk = blk >> 3;          // 0..31 within batch
    const int tid = threadIdx.x;
    const int wid = tid >> 6;
    const int lane = tid & 63;
    const int pairid = wid >> 1;        // 0..7
    const int half = wid & 1;           // 0 = dest[0,1024), 1 = dest[1024,2048)

    __shared__ float4 ds[NNP];          // 32 KB dest copy: (x,y,z, valid? |d|^2 : INF)
    __shared__ float sminV[WPB][TM];
    __shared__ int   sminI[WPB][TM];
    __shared__ float smom[WPB / 2][NPART];
    __shared__ float Sfin[NPART];
    __shared__ float Rt[12];
    __shared__ int anyf;

    if (tid == 0) anyf = 0;
    if (tid < 9) Rt[tid] = init_R[b * 9 + tid];
    if (tid < 3) Rt[9 + tid] = init_t[b * 3 + tid];
    __syncthreads();

    // stage dest once; fold validity into .w
    for (int n = tid; n < NNP; n += TPB) {
        const float dx = pc_dest[(b * 3 + 0) * NNP + n];
        const float dy = pc_dest[(b * 3 + 1) * NNP + n];
        const float dz = pc_dest[(b * 3 + 2) * NNP + n];
        const bool valid = (dx != 0.0f) && (dy != 0.0f) && (dz != 0.0f);
        const float dd = dx * dx + dy * dy + dz * dz;
        ds[n] = make_float4(dx, dy, dz, valid ? dd : INFINITY);
        const unsigned long long bal = __ballot(valid);
        if (lane == 0 && bal) atomicOr(&anyf, 1);
    }

    // this pair's 8 source points (wave-uniform; reference uses batch-0 source)
    const int m0 = cblk * (WPB / 2 * TM) + pairid * TM;
    float sx[TM], sy[TM], sz[TM];
    #pragma unroll
    for (int t = 0; t < TM; ++t) {
        sx[t] = pc_src[0 * MM + m0 + t];
        sy[t] = pc_src[1 * MM + m0 + t];
        sz[t] = pc_src[2 * MM + m0 + t];
    }
    __syncthreads();
    const float av = anyf ? 1.0f : 0.0f;
    const int base = half * HALF;

    for (int it = 0; it <= NITER; ++it) {
        // ---- transform: nx = -2*px etc. (argmin key drops the per-m constant pp) ----
        float nx[TM], ny[TM], nz[TM];
        #pragma unroll
        for (int t = 0; t < TM; ++t) {
            const float px = fmaf(Rt[0], sx[t], fmaf(Rt[1], sy[t], fmaf(Rt[2], sz[t], Rt[9])));
            const float py = fmaf(Rt[3], sx[t], fmaf(Rt[4], sy[t], fmaf(Rt[5], sz[t], Rt[10])));
            const float pz = fmaf(Rt[6], sx[t], fmaf(Rt[7], sy[t], fmaf(Rt[8], sz[t], Rt[11])));
            nx[t] = -2.0f * px; ny[t] = -2.0f * py; nz[t] = -2.0f * pz;
        }

        // ---- scan my half: 1 ds_read feeds 8 m-chains ----
        float best[TM]; int bidx[TM];
        #pragma unroll
        for (int t = 0; t < TM; ++t) { best[t] = INFINITY; bidx[t] = base + lane; }

        int j = base + lane;
        #pragma unroll 4
        for (int s = 0; s < STEPS; ++s, j += 64) {
            const float4 d = ds[j];
            #pragma unroll
            for (int t = 0; t < TM; ++t) {
                const float e = fmaf(nx[t], d.x, fmaf(ny[t], d.y, fmaf(nz[t], d.z, d.w)));
                if (e < best[t]) { best[t] = e; bidx[t] = j; }
            }
        }

        // ---- per-m cross-lane lex argmin (first-index tie-break) ----
        #pragma unroll
        for (int t = 0; t < TM; ++t) {
            float bv = best[t]; int bn = bidx[t];
            #pragma unroll
            for (int off = 32; off >= 1; off >>= 1) {
                const float ov = __shfl_xor(bv, off);
                const int on = __shfl_xor(bn, off);
                if (ov < bv || (ov == bv && on < bn)) { bv = ov; bn = on; }
            }
            best[t] = bv; bidx[t] = bn;
        }
        if (lane == 0) {
            #pragma unroll
            for (int t = 0; t < TM; ++t) { sminV[wid][t] = best[t]; sminI[wid][t] = bidx[t]; }
        }
        __syncthreads();

        // ---- even wave of each pair merges halves (tie -> even = lower index), moments ----
        if (!half) {
            float acc[NPART];
            #pragma unroll
            for (int k = 0; k < NPART; ++k) acc[k] = 0.0f;
            #pragma unroll
            for (int t = 0; t < TM; ++t) {
                float bv = best[t]; int bn = bidx[t];
                const float vO = sminV[wid + 1][t];
                const int iO = sminI[wid + 1][t];
                if (vO < bv) { bv = vO; bn = iO; }
                const float4 q = ds[bn];     // wave-uniform broadcast
                const float px = -0.5f * nx[t], py = -0.5f * ny[t], pz = -0.5f * nz[t];
                const float ex = px - q.x, ey = py - q.y, ez = pz - q.z;
                const float d2m = ex * ex + ey * ey + ez * ez;
                const float w = (d2m < THR2) ? av : 0.0f;
                acc[0] += w;
                acc[1] += w * sx[t];  acc[2] += w * sy[t];  acc[3] += w * sz[t];
                acc[4] += w * q.x;    acc[5] += w * q.y;    acc[6] += w * q.z;
                acc[7]  += w * sx[t] * q.x; acc[8]  += w * sx[t] * q.y; acc[9]  += w * sx[t] * q.z;
                acc[10] += w * sy[t] * q.x; acc[11] += w * sy[t] * q.y; acc[12] += w * sy[t] * q.z;
                acc[13] += w * sz[t] * q.x; acc[14] += w * sz[t] * q.y; acc[15] += w * sz[t] * q.z;
                acc[16] += w * d2m;
            }
            if (lane == 0) {
                #pragma unroll
                for (int k = 0; k < NPART; ++k) smom[pairid][k] = acc[k];
            }
        }
        __syncthreads();

        // ---- block moments -> device accumulator ----
        if (tid < NPART) {
            float s = 0.0f;
            #pragma unroll
            for (int p = 0; p < WPB / 2; ++p) s += smom[p][tid];
            __hip_atomic_fetch_add(&accum[(it * BB + b) * 32 + tid], s,
                                   __ATOMIC_RELAXED, __HIP_MEMORY_SCOPE_AGENT);
        }
        __syncthreads();    // all adds complete (barrier drains vmcnt)
        if (tid == 0) {
            __threadfence();
            __hip_atomic_fetch_add(&arrive[it * BB + b], 1u,
                                   __ATOMIC_RELEASE, __HIP_MEMORY_SCOPE_AGENT);
        }

        if (it == NITER) break;

        // ---- every block: wait for batch completion, read sums, redundant Kabsch ----
        if (tid == 0) {
            while (ld_acq_u(&arrive[it * BB + b]) < (unsigned)BPB)
                __builtin_amdgcn_s_sleep(4);
        }
        __syncthreads();
        if (tid < NPART) Sfin[tid] = ld_acq_f(&accum[(it * BB + b) * 32 + tid]);
        __syncthreads();
        if (tid == 0) {
            const float wsum = Sfin[0];
            if (wsum >= 0.5f) {
                const float safe = fmaxf(wsum, 1.0f);
                const float inv = 1.0f / safe;
                float mup[3], muq[3];
                for (int i = 0; i < 3; ++i) { mup[i] = Sfin[1 + i] * inv; muq[i] = Sfin[4 + i] * inv; }
                float H[3][3];
                for (int i = 0; i < 3; ++i)
                    for (int jj = 0; jj < 3; ++jj)
                        H[i][jj] = (Sfin[7 + i * 3 + jj] * inv) - mup[i] * muq[jj];
                float R[3][3];
                kabsch3f(H, R);
                for (int i = 0; i < 3; ++i) {
                    for (int jj = 0; jj < 3; ++jj) Rt[i * 3 + jj] = R[i][jj];
                    Rt[9 + i] = muq[i] - (R[i][0] * mup[0] + R[i][1] * mup[1] + R[i][2] * mup[2]);
                }
            }
        }
        __syncthreads();
    }

    // ---- outputs: batch leader only ----
    if (cblk == 0) {
        if (tid == 0) {
            while (ld_acq_u(&arrive[NITER * BB + b]) < (unsigned)BPB)
                __builtin_amdgcn_s_sleep(4);
            const float wsum = ld_acq_f(&accum[(NITER * BB + b) * 32 + 0]);
            const float wd2  = ld_acq_f(&accum[(NITER * BB + b) * 32 + 16]);
            const float safe = fmaxf(wsum, 1.0f);
            const float rmse = sqrtf(wd2 / safe);
            out[96 + b] = (wsum > 0.0f) ? rmse : __builtin_nanf("");
        }
        if (tid < 9) out[b * 9 + tid] = Rt[tid];
        if (tid < 3) out[72 + b * 3 + tid] = Rt[9 + tid];
    }
}

extern "C" void kernel_launch(void* const* d_in, const int* in_sizes, int n_in,
                              void* d_out, int out_size, void* d_ws, size_t ws_size,
                              hipStream_t stream) {
    const float* pc_src  = (const float*)d_in[0];
    const float* pc_dest = (const float*)d_in[1];
    const float* init_R  = (const float*)d_in[2];
    const float* init_t  = (const float*)d_in[3];
    float* out = (float*)d_out;

    float* accum     = (float*)d_ws;                 // ACC_N
    unsigned* arrive = (unsigned*)(accum + ACC_N);   // CN_N

    zero_kernel<<<(ACC_N + 1023) / 1024, 1024, 0, stream>>>(accum, arrive);

    void* args[] = {(void*)&pc_src, (void*)&pc_dest, (void*)&init_R, (void*)&init_t,
                    (void*)&accum, (void*)&arrive, (void*)&out};
    hipLaunchCooperativeKernel((const void*)icp_fused, dim3(GRIDB), dim3(TPB), args, 0, stream);
}